// Round 6
// baseline (302.066 us; speedup 1.0000x reference)
//
#include <hip/hip_runtime.h>
#include <hip/hip_fp16.h>
#include <cstdint>
#include <cstddef>

#define NB   4096   // batch
#define ND   128    // feature dim
#define OUTW 16384  // 4*NB output row width
#define CG   16     // col groups for the write pass
#define IT   8      // 64-col tiles per block (512 cols / 64)

// 10 * log2(e): logits = cos/T = 10*acc; exp(10a-10) = 2^(K2*a - K2)
#define K2   14.4269504088896341f

typedef _Float16 f16;
typedef __attribute__((ext_vector_type(2))) _Float16 f16x2;
typedef __attribute__((ext_vector_type(8))) _Float16 f16x8;
typedef __attribute__((ext_vector_type(4))) float   f32x4;

// ---------------------------------------------------------------------------
// Kernel 1: l2-normalize z1,z2 rows, cast to f16; also zero rowsum (8192 f32).
// One wave per row.
// ---------------------------------------------------------------------------
__global__ __launch_bounds__(256) void nrm_kernel(const float* __restrict__ z1,
                                                  const float* __restrict__ z2,
                                                  f16* __restrict__ ab,
                                                  float* __restrict__ rowsum) {
  if (threadIdx.x < 4) rowsum[blockIdx.x * 4 + threadIdx.x] = 0.0f;
  int row  = blockIdx.x * 4 + (threadIdx.x >> 6);
  int lane = threadIdx.x & 63;
  const float* src = (row < NB) ? (z1 + (size_t)row * ND)
                                : (z2 + (size_t)(row - NB) * ND);
  float2 v = ((const float2*)src)[lane];
  float ss = v.x * v.x + v.y * v.y;
#pragma unroll
  for (int off = 32; off; off >>= 1) ss += __shfl_xor(ss, off);
  float r = rsqrtf(fmaxf(ss, 1e-12f));
  f16x2 h;
  h.x = (f16)(v.x * r);
  h.y = (f16)(v.y * r);
  ((f16x2*)(ab + (size_t)row * ND))[lane] = h;
}

// ---------------------------------------------------------------------------
// Rowsum pass with TRANSPOSE SYMMETRY: exp(logits_ba) = exp(logits_ab)^T, so
// the ba quadrant is never computed.  Grid y = 96 strips:
//   m=0 (s 0..31):  ab tiles -> row-sums into rowsum[0..4095] (part1 cross)
//                   AND col-sums into rowsum[4096..] (part2 cross, via LDS acc)
//   m=1 (s 32..63): aa tiles (diag masked) -> rowsum[0..4095]
//   m=2 (s 64..95): bb tiles (diag masked) -> rowsum[4096..]
// Core GEMM identical to the verified swapped-operand kernel; lane holds
// row = l16, cols = quad*4+r (4 consecutive), so col-sums need a 4-stage
// shfl reduce over l16 per iteration, accumulated in LDS, flushed once.
// ---------------------------------------------------------------------------
__global__ __launch_bounds__(256, 2) void sum_kernel(const f16* __restrict__ ab,
                                                     float* __restrict__ rowsum) {
  __shared__ f16 Bs[2][64 * ND];   // 2 x 16 KB
  __shared__ float cs_col[512];    // 2 KB col-sum accumulator (m==0 only)

  const int t    = threadIdx.x;
  const int wave = t >> 6;
  const int lane = t & 63;
  const int wr   = wave >> 1;
  const int wc   = wave & 1;
  const int quad = lane >> 4;
  const int l16  = lane & 15;

  const int s     = blockIdx.y;            // 0..95
  const int m     = s >> 5;                // 0=ab, 1=aa, 2=bb
  const int r0    = (s & 31) * 128;        // query row base in [0,4096)
  const int cbase = blockIdx.x * 512;      // col base within the 4096-col matrix
  // m=0: Q=a,K=b; m=1: Q=a,K=a; m=2: Q=b,K=b
  const f16* Q  = ab + (size_t)(m == 2 ? NB * ND : 0);
  const f16* Kp = ab + (size_t)(m == 1 ? 0 : NB * ND);
  const bool diag = (m != 0);
  const bool docol = (m == 0);

  // ---- A fragments: K=128 fully in registers (L2-hot global reads).
  f16x8 af[4][4];
  {
    const int arow = r0 + wr * 64 + l16;
#pragma unroll
    for (int mi = 0; mi < 4; ++mi)
#pragma unroll
      for (int ks = 0; ks < 4; ++ks)
        af[mi][ks] = *(const f16x8*)(Q + (size_t)(arow + mi * 16) * ND +
                                     ks * 32 + quad * 8);
  }

  const int sub = t >> 4;   // 0..15
  const int oct = t & 15;
  auto stage_b = [&](f16* buf, int kc0) {
#pragma unroll
    for (int i = 0; i < 4; ++i) {
      int rowl = i * 16 + sub;
      int goct = oct ^ (rowl & 15);
      __builtin_amdgcn_global_load_lds(
          (const __attribute__((address_space(1))) void*)(
              Kp + (size_t)(kc0 + rowl) * ND + goct * 8),
          (__attribute__((address_space(3))) void*)(buf + rowl * ND + oct * 8),
          16, 0, 0);
    }
  };

  float ps[4];
#pragma unroll
  for (int mi = 0; mi < 4; ++mi) ps[mi] = 0.0f;

  stage_b(Bs[0], cbase);
  cs_col[t] = 0.0f;
  cs_col[t + 256] = 0.0f;
  __syncthreads();

  for (int it = 0; it < IT; ++it) {
    if (it + 1 < IT) stage_b(Bs[(it + 1) & 1], cbase + (it + 1) * 64);

    const f16* buf = Bs[it & 1];
    f32x4 acc[4][2] = {};
#pragma unroll
    for (int ks = 0; ks < 4; ++ks) {
      int sw = (((ks * 4 + quad) ^ l16)) * 8;
      f16x8 bf0 = *(const f16x8*)(buf + (wc * 32 + l16) * ND + sw);
      f16x8 bf1 = *(const f16x8*)(buf + (wc * 32 + 16 + l16) * ND + sw);
#pragma unroll
      for (int mi = 0; mi < 4; ++mi) {
        acc[mi][0] = __builtin_amdgcn_mfma_f32_16x16x32_f16(bf0, af[mi][ks],
                                                            acc[mi][0], 0, 0, 0);
        acc[mi][1] = __builtin_amdgcn_mfma_f32_16x16x32_f16(bf1, af[mi][ks],
                                                            acc[mi][1], 0, 0, 0);
      }
    }

    const int c0m = cbase + it * 64;                 // within-matrix col base
    const bool dtile = diag && (c0m == r0 || c0m == r0 + 64);

    float cpart[8];
#pragma unroll
    for (int v = 0; v < 8; ++v) cpart[v] = 0.0f;

#pragma unroll
    for (int mi = 0; mi < 4; ++mi) {
      const int row_l = wr * 64 + mi * 16 + l16;
#pragma unroll
      for (int ni = 0; ni < 2; ++ni) {
        const int cq = wc * 32 + ni * 16 + quad * 4;
#pragma unroll
        for (int r = 0; r < 4; ++r) {
          float e = __builtin_amdgcn_exp2f(fmaf(acc[mi][ni][r], K2, -K2));
          if (dtile && (c0m + cq + r == r0 + row_l)) e = 0.0f;
          ps[mi] += e;
          cpart[ni * 4 + r] += e;
        }
      }
    }

    if (docol) {
      // reduce cpart over the 16 rows held by l16; flush to LDS col acc.
#pragma unroll
      for (int v = 0; v < 8; ++v) {
        float x = cpart[v];
        x += __shfl_xor(x, 1);
        x += __shfl_xor(x, 2);
        x += __shfl_xor(x, 4);
        x += __shfl_xor(x, 8);
        cpart[v] = x;
      }
      if (l16 == 0) {
#pragma unroll
        for (int v = 0; v < 8; ++v) {
          int col_l = it * 64 + wc * 32 + (v >> 2) * 16 + quad * 4 + (v & 3);
          atomicAdd(&cs_col[col_l], cpart[v]);
        }
      }
    }
    __syncthreads();
  }

  // row-sum flush: sum over the 4 quads, one atomic per row per wave.
  const int rbase = (m == 2) ? NB + r0 : r0;
#pragma unroll
  for (int mi = 0; mi < 4; ++mi) {
    float v = ps[mi];
    v += __shfl_xor(v, 16);
    v += __shfl_xor(v, 32);
    if (quad == 0) {
      int row_l = wr * 64 + mi * 16 + l16;
      atomicAdd(&rowsum[rbase + row_l], v);
    }
  }

  // col-sum flush (ab blocks only): rowsum2[col] += cs_col[col].
  if (docol) {
    atomicAdd(&rowsum[NB + cbase + t], cs_col[t]);
    atomicAdd(&rowsum[NB + cbase + t + 256], cs_col[t + 256]);
  }
}

// ---------------------------------------------------------------------------
// Write pass (verified, swapped-operand, 8x global_store_dwordx4 epilogue).
// ---------------------------------------------------------------------------
__global__ __launch_bounds__(256, 2) void wr_kernel(const f16* __restrict__ ab,
                                                    float* __restrict__ rowsum,
                                                    float* __restrict__ out) {
  __shared__ f16 Bs[2][64 * ND];   // 2 x 16 KB
  __shared__ float cs[128];

  const int t    = threadIdx.x;
  const int wave = t >> 6;
  const int lane = t & 63;
  const int wr   = wave >> 1;
  const int wc   = wave & 1;
  const int quad = lane >> 4;
  const int l16  = lane & 15;

  const int rt    = blockIdx.y;            // 0..63
  const int type  = rt >> 5;               // 0 = part1 (query a), 1 = part2 (b)
  const int r0    = (rt & 31) * 128;       // query row base in [0,4096)
  const int g     = blockIdx.x;            // 0..CG-1
  const int h2    = (g >= CG / 2) ? 1 : 0; // own-matrix half (diag masked)
  const int cbl   = g * (8192 / CG);       // logical col base (0..8191)
  const int cbase = cbl & (NB - 1);        // within-matrix col base
  const f16* Q  = ab + (size_t)type * NB * ND;
  const f16* Kp = ab + (size_t)(h2 ? type : (type ^ 1)) * NB * ND;

  f16x8 af[4][4];
  {
    const int arow = r0 + wr * 64 + l16;
#pragma unroll
    for (int mi = 0; mi < 4; ++mi)
#pragma unroll
      for (int ks = 0; ks < 4; ++ks)
        af[mi][ks] = *(const f16x8*)(Q + (size_t)(arow + mi * 16) * ND +
                                     ks * 32 + quad * 8);
  }

  const int sub = t >> 4;   // 0..15
  const int oct = t & 15;
  auto stage_b = [&](f16* buf, int kc0) {
#pragma unroll
    for (int i = 0; i < 4; ++i) {
      int rowl = i * 16 + sub;
      int goct = oct ^ (rowl & 15);
      __builtin_amdgcn_global_load_lds(
          (const __attribute__((address_space(1))) void*)(
              Kp + (size_t)(kc0 + rowl) * ND + goct * 8),
          (__attribute__((address_space(3))) void*)(buf + rowl * ND + oct * 8),
          16, 0, 0);
    }
  };

  stage_b(Bs[0], cbase);
  if (t < 128) cs[t] = -__log2f(rowsum[rt * 128 + t]) - K2;
  __syncthreads();

  for (int it = 0; it < IT; ++it) {
    if (it + 1 < IT) stage_b(Bs[(it + 1) & 1], cbase + (it + 1) * 64);

    const f16* buf = Bs[it & 1];
    f32x4 acc[4][2] = {};
#pragma unroll
    for (int ks = 0; ks < 4; ++ks) {
      int sw = (((ks * 4 + quad) ^ l16)) * 8;
      f16x8 bf0 = *(const f16x8*)(buf + (wc * 32 + l16) * ND + sw);
      f16x8 bf1 = *(const f16x8*)(buf + (wc * 32 + 16 + l16) * ND + sw);
#pragma unroll
      for (int mi = 0; mi < 4; ++mi) {
        acc[mi][0] = __builtin_amdgcn_mfma_f32_16x16x32_f16(bf0, af[mi][ks],
                                                            acc[mi][0], 0, 0, 0);
        acc[mi][1] = __builtin_amdgcn_mfma_f32_16x16x32_f16(bf1, af[mi][ks],
                                                            acc[mi][1], 0, 0, 0);
      }
    }

    const int c0m = cbase + it * 64;                 // within-matrix col base
    const bool dtile = h2 && (c0m == r0 || c0m == r0 + 64);

#pragma unroll
    for (int mi = 0; mi < 4; ++mi) {
      const int row_l = wr * 64 + mi * 16 + l16;
      const float c = cs[row_l];
      float* orow = out + (size_t)(r0 + row_l) * OUTW + (size_t)type * 8192 +
                    cbl + it * 64;
#pragma unroll
      for (int ni = 0; ni < 2; ++ni) {
        const int cq = wc * 32 + ni * 16 + quad * 4;
        f32x4 o;
#pragma unroll
        for (int r = 0; r < 4; ++r) {
          float e = __builtin_amdgcn_exp2f(fmaf(acc[mi][ni][r], K2, c));
          if (dtile && (c0m + cq + r == r0 + row_l)) e = 0.0f;
          o[r] = e;
        }
        *(f32x4*)(orow + cq) = o;
      }
    }
    __syncthreads();
  }
}

// ---------------------------------------------------------------------------
extern "C" void kernel_launch(void* const* d_in, const int* in_sizes, int n_in,
                              void* d_out, int out_size, void* d_ws, size_t ws_size,
                              hipStream_t stream) {
  const float* z1 = (const float*)d_in[0];
  const float* z2 = (const float*)d_in[1];
  float* out = (float*)d_out;

  f16* ab = (f16*)d_ws;                                   // 8192x128 f16 = 2 MB
  float* rowsum = (float*)((char*)d_ws + (size_t)8192 * ND * sizeof(f16)); // 32 KB

  nrm_kernel<<<2048, 256, 0, stream>>>(z1, z2, ab, rowsum);
  sum_kernel<<<dim3(8, 96), 256, 0, stream>>>(ab, rowsum);
  wr_kernel<<<dim3(CG, 64), 256, 0, stream>>>(ab, rowsum, out);
}